// Round 6
// baseline (148.354 us; speedup 1.0000x reference)
//
#include <hip/hip_runtime.h>

#define NN 2048
#define FF 64
#define HH 32
#define OO 32

// Workspace layout (bytes):
//   0      : f_sums [2048*32] f32  (256 KB)
//   262144 : q_pos  [64*32] f32
//   270336 : q_neg  [64*32] f32
//   278528 : qb     [32] f32
//   278656 : cpr    [2] f32
//   278664 : flags  [2] int
//   278672 : bar    [65] u32  (producer-done MAGIC flags)
#define WS_FSUMS 0
#define WS_QPOS  262144
#define WS_QNEG  270336
#define WS_QB    278528
#define WS_CPR   278656
#define WS_FLAGS 278664
#define WS_BAR   278672

#define MAGIC 0x13579BDFu

// ---------------------------------------------------------------------------
// Kernel 1 (fused): precompute + zero-out + f_sums, single launch.
//  - all 256 blocks: zero their slice of out (rho atomically accumulates).
//  - blocks 0..63: produce q_pos/q_neg for feature f = blockIdx (LDS-staged
//    float4 loads), then release-publish bar[f] = MAGIC.
//  - block 64: cpr (exact rho slopes), qb, zero-bias flags; publish bar[64].
//  - all blocks: parallel spin-acquire on bar[0..64] (one flag per thread;
//    MAGIC != 0xAAAAAAAA poison, so re-poisoned ws can't false-trigger),
//    then compute f_sums for 8 nodes (fast path or exact fallback).
// Deadlock-free: 256 blocks x 256 threads always co-resident (>=1 block/CU).
// ---------------------------------------------------------------------------
__global__ __launch_bounds__(256) void fused_pre_fsums_kernel(
    const float* __restrict__ x,
    const float* __restrict__ fW1, const float* __restrict__ fb1,
    const float* __restrict__ fW2, const float* __restrict__ fb2,
    const float* __restrict__ fW3, const float* __restrict__ fb3,
    const float* __restrict__ rW1, const float* __restrict__ rb1,
    const float* __restrict__ rW2, const float* __restrict__ rb2,
    const float* __restrict__ rW3,
    float* __restrict__ q_pos, float* __restrict__ q_neg,
    float* __restrict__ qb, float* __restrict__ cpr,
    int* __restrict__ flags, unsigned* __restrict__ bar,
    float* __restrict__ f_sums, float* __restrict__ out)
{
    __shared__ float sA[HH * HH];      // fW2 slab / rW2   (4 KB)
    __shared__ float sB[FF * OO];      // fW3 slab / fb3   (8 KB)
    __shared__ float sC[128];          // vs / small weights
    __shared__ float qs[2][FF * OO];   // q tables for fsums (16 KB)
    __shared__ float xs[8 * FF];       // x slice (2 KB)
    __shared__ int sflags[2];

    const int t = threadIdx.x;
    const int b = blockIdx.x;

    // ---- phase 0: zero out slice (16384 float4 over 256 blocks) ----
    if (t < 64)
        ((float4*)out)[b * 64 + t] = make_float4(0.f, 0.f, 0.f, 0.f);

    // ---- phase 1: producers ----
    if (b < FF) {
        const int f = b;
        ((float4*)sA)[t] = ((const float4*)&fW2[f * HH * HH])[t];
        if (t < 256) ((float4*)sB)[t & 255] =
            ((const float4*)&fW3[f * HH * OO])[t & 255];
        if (t < HH) sC[64 + t] = fW1[f * HH + t];
        __syncthreads();

        if (t < 64) {
            const int s = t >> 5;      // 0=pos, 1=neg
            const int g = t & 31;
            float v = 0.f;
#pragma unroll
            for (int h = 0; h < HH; ++h) {
                const float w1 = sC[64 + h];
                const float a = s ? fminf(w1, 0.f) : fmaxf(w1, 0.f);
                v = fmaf(a, sA[h * HH + g], v);
            }
            sC[t] = s ? fminf(v, 0.f) : fmaxf(v, 0.f);
        }
        __syncthreads();
        if (t < 64) {
            const int s = t >> 5;
            const int o = t & 31;
            float q = 0.f;
#pragma unroll
            for (int g = 0; g < HH; ++g)
                q = fmaf(sC[s * 32 + g], sB[g * OO + o], q);
            if (s) q_neg[f * OO + o] = q;
            else   q_pos[f * OO + o] = q;
        }
        __syncthreads();
        if (t == 0) {
            __threadfence();           // release q[f]
            __hip_atomic_store(&bar[f], MAGIC, __ATOMIC_RELEASE,
                               __HIP_MEMORY_SCOPE_AGENT);
        }
    } else if (b == FF) {
        if (t == 0) { sflags[0] = 1; sflags[1] = 1; }
        ((float4*)sA)[t] = ((const float4*)rW2)[t];
        ((float4*)sB)[t] = ((const float4*)fb3)[t];
        ((float4*)sB)[t + 256] = ((const float4*)fb3)[t + 256];
        if (t < HH) sC[64 + t] = rW1[t];
        else if (t < 64) sC[96 + (t - HH)] = rW3[t - HH];
        __syncthreads();

        if (t < 64) {
            const int s = t >> 5;
            const int g = t & 31;
            float v = 0.f;
#pragma unroll
            for (int h = 0; h < HH; ++h) {
                const float w1 = sC[64 + h];
                const float a = s ? fminf(w1, 0.f) : fmaxf(w1, 0.f);
                v = fmaf(a, sA[h * HH + g], v);
            }
            sC[t] = s ? fminf(v, 0.f) : fmaxf(v, 0.f);
        } else if (t < 96) {
            const int o = t - 64;
            float a = 0.f;
#pragma unroll
            for (int f = 0; f < FF; ++f) a += sB[f * OO + o];
            qb[o] = a;
        } else if (t < 160) {
            const int i = t - 96;
            bool bad;
            if (i < HH) bad = (rb1[i] != 0.f);
            else        bad = (rb2[i - HH] != 0.f);
            if (bad) sflags[1] = 0;
        } else {
            const float4* b1 = (const float4*)fb1;
            const float4* b2 = (const float4*)fb2;
            bool bad = false;
            for (int i = t - 160; i < (FF * HH) / 4; i += 96) {
                const float4 a4 = b1[i], b4 = b2[i];
                bad |= (a4.x != 0.f) | (a4.y != 0.f) |
                       (a4.z != 0.f) | (a4.w != 0.f);
                bad |= (b4.x != 0.f) | (b4.y != 0.f) |
                       (b4.z != 0.f) | (b4.w != 0.f);
            }
            if (bad) sflags[0] = 0;
        }
        __syncthreads();

        if (t < 2) {
            float c = 0.f;
#pragma unroll
            for (int g = 0; g < HH; ++g)
                c = fmaf(sC[t * 32 + g], sC[96 + g], c);
            cpr[t] = c;
        }
        if (t == 0) {
            flags[0] = sflags[0]; flags[1] = sflags[1];
            __threadfence();           // release cpr/qb/flags
            __hip_atomic_store(&bar[FF], MAGIC, __ATOMIC_RELEASE,
                               __HIP_MEMORY_SCOPE_AGENT);
        }
    }

    // ---- phase 2: barrier (parallel spin, one flag per thread) ----
    if (t < FF + 1) {
        while (__hip_atomic_load(&bar[t], __ATOMIC_ACQUIRE,
                                 __HIP_MEMORY_SCOPE_AGENT) != MAGIC) {}
    }
    __syncthreads();

    // ---- phase 3: f_sums for 8 nodes ----
    const int n0 = b * 8;

    if (flags[0]) {
        ((float4*)qs[0])[t]       = ((const float4*)q_pos)[t];
        ((float4*)qs[0])[t + 256] = ((const float4*)q_pos)[t + 256];
        ((float4*)qs[1])[t]       = ((const float4*)q_neg)[t];
        ((float4*)qs[1])[t + 256] = ((const float4*)q_neg)[t + 256];
        if (t < 128) ((float4*)xs)[t] = ((const float4*)&x[n0 * FF])[t];
        __syncthreads();

        const int r = t >> 5;
        const int o = t & 31;
        float acc = qb[o];
#pragma unroll
        for (int f = 0; f < FF; ++f) {
            const float xv = xs[r * FF + f];
            const float qv = (xv >= 0.f) ? qs[0][f * OO + o]
                                         : qs[1][f * OO + o];
            acc = fmaf(xv, qv, acc);
        }
        f_sums[(n0 + r) * OO + o] = acc;
        return;
    }

    // ---- exact fallback: wave-per-node, 2 passes ----
    const int wave = t >> 6;
    const int lane = t & 63;
    for (int pass = 0; pass < 2; ++pass) {
        const int n = n0 + pass * 4 + wave;
        const int f = lane;
        const float xv = x[n * FF + f];

        float h1[HH];
#pragma unroll
        for (int h = 0; h < HH; ++h)
            h1[h] = fmaxf(xv * fW1[f * HH + h] + fb1[f * HH + h], 0.f);

        float h2[HH];
#pragma unroll
        for (int g = 0; g < HH; ++g) h2[g] = fb2[f * HH + g];
#pragma unroll
        for (int h = 0; h < HH; ++h) {
            const float a = h1[h];
            const float* __restrict__ w = &fW2[(f * HH + h) * HH];
#pragma unroll
            for (int g = 0; g < HH; ++g) h2[g] += a * w[g];
        }
#pragma unroll
        for (int g = 0; g < HH; ++g) h2[g] = fmaxf(h2[g], 0.f);

        float acc[OO];
#pragma unroll
        for (int o = 0; o < OO; ++o) acc[o] = fb3[f * OO + o];
#pragma unroll
        for (int h = 0; h < HH; ++h) {
            const float a = h2[h];
            const float* __restrict__ w = &fW3[(f * HH + h) * OO];
#pragma unroll
            for (int o = 0; o < OO; ++o) acc[o] += a * w[o];
        }

#pragma unroll
        for (int o = 0; o < OO; ++o) {
            float v = acc[o];
#pragma unroll
            for (int off = 32; off >= 1; off >>= 1)
                v += __shfl_xor(v, off, 64);
            acc[o] = v;
        }
        if (lane == 0) {
#pragma unroll
            for (int o = 0; o < OO; ++o)
                f_sums[n * OO + o] = acc[o];
        }
    }
}

// ---------------------------------------------------------------------------
// Kernel 2: rho + normalize + matmul. 512 blocks (32 row-tiles x 16 k-splits).
// float4 staging of dmat/norm; atomicAdd into the pre-zeroed out.
// Near both ceilings: 32 MB HBM read (5.2 us @ 6.3 TB/s) and ~3.4 us VALU.
// ---------------------------------------------------------------------------
__global__ __launch_bounds__(256) void rho_all_kernel(
    const float* __restrict__ dmat, const float* __restrict__ norm,
    const float* __restrict__ f_sums,
    const float* __restrict__ cpr, const float* __restrict__ rb3,
    const float* __restrict__ rW1, const float* __restrict__ rb1,
    const float* __restrict__ rW2, const float* __restrict__ rb2,
    const float* __restrict__ rW3,
    const int* __restrict__ flags,
    float* __restrict__ out)
{
    const int t = threadIdx.x;

    if (flags[1]) {
        __shared__ float Bt[128 * 66];   // [j][r], padded stride 66
        __shared__ float fsL[128 * 32];  // [j][o]

        const int rt = blockIdx.x >> 4;  // 0..31
        const int kb = blockIdx.x & 15;  // 0..15
        const int n0 = rt * 64;
        const int m0 = kb * 128;

        const float cp = cpr[0], cn = cpr[1], b3 = rb3[0];

        {
            const float4* src = (const float4*)&f_sums[m0 * OO];
            float4* dst = (float4*)fsL;
#pragma unroll
            for (int i = 0; i < 4; ++i)
                dst[i * 256 + t] = src[i * 256 + t];
        }

#pragma unroll
        for (int it = 0; it < 8; ++it) {
            const int idx4 = it * 256 + t;
            const int r = idx4 >> 5;
            const int j4 = (idx4 & 31) * 4;
            const long g = (long)(n0 + r) * NN + (m0 + j4);
            const float4 d4 = *(const float4*)&dmat[g];
            const float4 n4 = *(const float4*)&norm[g];
            Bt[(j4 + 0) * 66 + r] =
                fmaf(d4.x >= 0.f ? cp : cn, d4.x, b3) / n4.x;
            Bt[(j4 + 1) * 66 + r] =
                fmaf(d4.y >= 0.f ? cp : cn, d4.y, b3) / n4.y;
            Bt[(j4 + 2) * 66 + r] =
                fmaf(d4.z >= 0.f ? cp : cn, d4.z, b3) / n4.z;
            Bt[(j4 + 3) * 66 + r] =
                fmaf(d4.w >= 0.f ? cp : cn, d4.w, b3) / n4.w;
        }
        __syncthreads();

        const int oq = t & 7;
        const int rg = t >> 3;
        const int r0 = rg * 2;

        float4 acc0 = make_float4(0.f, 0.f, 0.f, 0.f);
        float4 acc1 = make_float4(0.f, 0.f, 0.f, 0.f);

#pragma unroll 4
        for (int j = 0; j < 128; ++j) {
            const float2 b  = *(const float2*)&Bt[j * 66 + r0];
            const float4 fv = *(const float4*)&fsL[j * 32 + oq * 4];
            acc0.x = fmaf(b.x, fv.x, acc0.x);
            acc0.y = fmaf(b.x, fv.y, acc0.y);
            acc0.z = fmaf(b.x, fv.z, acc0.z);
            acc0.w = fmaf(b.x, fv.w, acc0.w);
            acc1.x = fmaf(b.y, fv.x, acc1.x);
            acc1.y = fmaf(b.y, fv.y, acc1.y);
            acc1.z = fmaf(b.y, fv.z, acc1.z);
            acc1.w = fmaf(b.y, fv.w, acc1.w);
        }

        float* p = &out[(n0 + r0) * OO + oq * 4];
        atomicAdd(p + 0, acc0.x);
        atomicAdd(p + 1, acc0.y);
        atomicAdd(p + 2, acc0.z);
        atomicAdd(p + 3, acc0.w);
        atomicAdd(p + OO + 0, acc1.x);
        atomicAdd(p + OO + 1, acc1.y);
        atomicAdd(p + OO + 2, acc1.z);
        atomicAdd(p + OO + 3, acc1.w);
        return;
    }

    // ---- exact fallback: 4 rows per block, full K ----
    __shared__ float red[4][OO];
    const int wave = t >> 6;
    const int lane = t & 63;

    for (int rr = 0; rr < 4; ++rr) {
        const int n = blockIdx.x * 4 + rr;

        float acc[OO];
#pragma unroll
        for (int o = 0; o < OO; ++o) acc[o] = 0.f;

#pragma unroll 1
        for (int m0 = 0; m0 < NN; m0 += 256) {
            const int m = m0 + t;
            const float d = dmat[(long)n * NN + m];

            float h1[HH];
#pragma unroll
            for (int h = 0; h < HH; ++h)
                h1[h] = fmaxf(d * rW1[h] + rb1[h], 0.f);

            float h2[HH];
#pragma unroll
            for (int g = 0; g < HH; ++g) h2[g] = rb2[g];
#pragma unroll
            for (int h = 0; h < HH; ++h) {
                const float a = h1[h];
#pragma unroll
                for (int g = 0; g < HH; ++g) h2[g] += a * rW2[h * HH + g];
            }

            float r = rb3[0];
#pragma unroll
            for (int h = 0; h < HH; ++h)
                r += fmaxf(h2[h], 0.f) * rW3[h];

            r /= norm[(long)n * NN + m];

            const float* __restrict__ fs = &f_sums[m * OO];
#pragma unroll
            for (int o = 0; o < OO; ++o) acc[o] += r * fs[o];
        }

#pragma unroll
        for (int o = 0; o < OO; ++o) {
            float v = acc[o];
#pragma unroll
            for (int off = 32; off >= 1; off >>= 1)
                v += __shfl_xor(v, off, 64);
            acc[o] = v;
        }
        if (lane == 0) {
#pragma unroll
            for (int o = 0; o < OO; ++o) red[wave][o] = acc[o];
        }
        __syncthreads();
        if (t < OO)
            out[n * OO + t] = red[0][t] + red[1][t] + red[2][t] + red[3][t];
        __syncthreads();
    }
}

extern "C" void kernel_launch(void* const* d_in, const int* in_sizes, int n_in,
                              void* d_out, int out_size, void* d_ws, size_t ws_size,
                              hipStream_t stream) {
    const float* x    = (const float*)d_in[0];
    const float* dmat = (const float*)d_in[1];
    const float* norm = (const float*)d_in[2];
    const float* fW1  = (const float*)d_in[3];
    const float* fb1  = (const float*)d_in[4];
    const float* fW2  = (const float*)d_in[5];
    const float* fb2  = (const float*)d_in[6];
    const float* fW3  = (const float*)d_in[7];
    const float* fb3  = (const float*)d_in[8];
    const float* rW1  = (const float*)d_in[9];
    const float* rb1  = (const float*)d_in[10];
    const float* rW2  = (const float*)d_in[11];
    const float* rb2  = (const float*)d_in[12];
    const float* rW3  = (const float*)d_in[13];
    const float* rb3  = (const float*)d_in[14];

    char* ws = (char*)d_ws;
    float*    f_sums = (float*)(ws + WS_FSUMS);
    float*    q_pos  = (float*)(ws + WS_QPOS);
    float*    q_neg  = (float*)(ws + WS_QNEG);
    float*    qb     = (float*)(ws + WS_QB);
    float*    cpr    = (float*)(ws + WS_CPR);
    int*      flags  = (int*)(ws + WS_FLAGS);
    unsigned* bar    = (unsigned*)(ws + WS_BAR);

    float* out = (float*)d_out;

    fused_pre_fsums_kernel<<<NN / 8, 256, 0, stream>>>(
        x, fW1, fb1, fW2, fb2, fW3, fb3, rW1, rb1, rW2, rb2, rW3,
        q_pos, q_neg, qb, cpr, flags, bar, f_sums, out);

    rho_all_kernel<<<512, 256, 0, stream>>>(
        dmat, norm, f_sums, cpr, rb3, rW1, rb1, rW2, rb2, rW3, flags, out);
}

// Round 7
// 135.805 us; speedup vs baseline: 1.0924x; 1.0924x over previous
//
#include <hip/hip_runtime.h>

#define NN 2048
#define FF 64
#define HH 32
#define OO 32

// Workspace layout (bytes):
//   0      : f_sums [2048*32] f32  (256 KB)
//   262144 : q_pos  [64*32] f32
//   270336 : q_neg  [64*32] f32
//   278528 : qb     [32] f32
//   278656 : cpr    [2] f32
//   278664 : flags  [2] int
#define WS_FSUMS 0
#define WS_QPOS  262144
#define WS_QNEG  270336
#define WS_QB    278528
#define WS_CPR   278656
#define WS_FLAGS 278664

// NOTE (round 6 lesson): fusing precompute+fsums with an in-kernel
// producer/consumer spin barrier REGRESSED +20 us (cross-XCD flag polling
// serializes on L2 misses). Separate launches are cheaper (~1.5 us/node).

// ---------------------------------------------------------------------------
// Kernel 1: precompute + zero out.  Blocks 0..63: per-feature q tables
// (LDS-staged float4 loads). Block 64: cpr/qb/flags.
// ---------------------------------------------------------------------------
__global__ __launch_bounds__(256) void precompute_all_kernel(
    const float* __restrict__ fW1, const float* __restrict__ fb1,
    const float* __restrict__ fW2, const float* __restrict__ fb2,
    const float* __restrict__ fW3, const float* __restrict__ fb3,
    const float* __restrict__ rW1, const float* __restrict__ rb1,
    const float* __restrict__ rW2, const float* __restrict__ rb2,
    const float* __restrict__ rW3,
    float* __restrict__ q_pos, float* __restrict__ q_neg,
    float* __restrict__ qb, float* __restrict__ cpr,
    int* __restrict__ flags, float* __restrict__ out)
{
    __shared__ float sA[HH * HH];      // fW2 slab / rW2
    __shared__ float sB[FF * OO];      // fW3 slab (1024) / fb3 (2048)
    __shared__ float sC[128];          // vs / vsr + small weights
    __shared__ int sflags[2];

    const int t = threadIdx.x;

    if (blockIdx.x < FF) {
        const int f = blockIdx.x;
        ((float4*)out)[blockIdx.x * 256 + t] =
            make_float4(0.f, 0.f, 0.f, 0.f);
        ((float4*)sA)[t] = ((const float4*)&fW2[f * HH * HH])[t];
        ((float4*)sB)[t] = ((const float4*)&fW3[f * HH * OO])[t];
        if (t < HH) sC[64 + t] = fW1[f * HH + t];
        __syncthreads();

        if (t < 64) {
            const int s = t >> 5;      // 0=pos, 1=neg
            const int g = t & 31;
            float v = 0.f;
#pragma unroll
            for (int h = 0; h < HH; ++h) {
                const float w1 = sC[64 + h];
                const float a = s ? fminf(w1, 0.f) : fmaxf(w1, 0.f);
                v = fmaf(a, sA[h * HH + g], v);
            }
            sC[t] = s ? fminf(v, 0.f) : fmaxf(v, 0.f);
        }
        __syncthreads();
        if (t < 64) {
            const int s = t >> 5;
            const int o = t & 31;
            float q = 0.f;
#pragma unroll
            for (int g = 0; g < HH; ++g)
                q = fmaf(sC[s * 32 + g], sB[g * OO + o], q);
            if (s) q_neg[f * OO + o] = q;
            else   q_pos[f * OO + o] = q;
        }
        return;
    }

    // ---- block 64: misc ----
    if (t == 0) { sflags[0] = 1; sflags[1] = 1; }
    ((float4*)sA)[t] = ((const float4*)rW2)[t];
    ((float4*)sB)[t] = ((const float4*)fb3)[t];
    ((float4*)sB)[t + 256] = ((const float4*)fb3)[t + 256];
    if (t < HH) sC[64 + t] = rW1[t];
    else if (t < 64) sC[96 + (t - HH)] = rW3[t - HH];
    __syncthreads();

    if (t < 64) {
        const int s = t >> 5;
        const int g = t & 31;
        float v = 0.f;
#pragma unroll
        for (int h = 0; h < HH; ++h) {
            const float w1 = sC[64 + h];
            const float a = s ? fminf(w1, 0.f) : fmaxf(w1, 0.f);
            v = fmaf(a, sA[h * HH + g], v);
        }
        sC[t] = s ? fminf(v, 0.f) : fmaxf(v, 0.f);
    } else if (t < 96) {
        const int o = t - 64;
        float a = 0.f;
#pragma unroll
        for (int f = 0; f < FF; ++f) a += sB[f * OO + o];
        qb[o] = a;
    } else if (t < 160) {
        const int i = t - 96;
        bool bad;
        if (i < HH) bad = (rb1[i] != 0.f);
        else        bad = (rb2[i - HH] != 0.f);
        if (bad) sflags[1] = 0;
    } else {
        const float4* b1 = (const float4*)fb1;
        const float4* b2 = (const float4*)fb2;
        bool bad = false;
        for (int i = t - 160; i < (FF * HH) / 4; i += 96) {
            const float4 a = b1[i], b = b2[i];
            bad |= (a.x != 0.f) | (a.y != 0.f) | (a.z != 0.f) | (a.w != 0.f);
            bad |= (b.x != 0.f) | (b.y != 0.f) | (b.z != 0.f) | (b.w != 0.f);
        }
        if (bad) sflags[0] = 0;
    }
    __syncthreads();

    if (t < 2) {
        float c = 0.f;
#pragma unroll
        for (int g = 0; g < HH; ++g)
            c = fmaf(sC[t * 32 + g], sC[96 + g], c);
        cpr[t] = c;
    }
    if (t == 0) { flags[0] = sflags[0]; flags[1] = sflags[1]; }
}

// ---------------------------------------------------------------------------
// Kernel 2: f_sums. Fast path: stage q tables (16 KB) + x (2 KB) into LDS
// with float4 cooperative loads; inner loop pure LDS. 256 blocks x 8 nodes.
// ---------------------------------------------------------------------------
__global__ __launch_bounds__(256) void fsums_all_kernel(
    const float* __restrict__ x,
    const float* __restrict__ q_pos, const float* __restrict__ q_neg,
    const float* __restrict__ qb,
    const float* __restrict__ fW1, const float* __restrict__ fb1,
    const float* __restrict__ fW2, const float* __restrict__ fb2,
    const float* __restrict__ fW3, const float* __restrict__ fb3,
    const int* __restrict__ flags,
    float* __restrict__ f_sums)
{
    const int t = threadIdx.x;
    const int n0 = blockIdx.x * 8;

    if (flags[0]) {
        __shared__ float qs[2][FF * OO];   // 2 x 8 KB
        __shared__ float xs[8 * FF];       // 2 KB
        ((float4*)qs[0])[t]       = ((const float4*)q_pos)[t];
        ((float4*)qs[0])[t + 256] = ((const float4*)q_pos)[t + 256];
        ((float4*)qs[1])[t]       = ((const float4*)q_neg)[t];
        ((float4*)qs[1])[t + 256] = ((const float4*)q_neg)[t + 256];
        if (t < 128) ((float4*)xs)[t] = ((const float4*)&x[n0 * FF])[t];
        __syncthreads();

        const int r = t >> 5;
        const int o = t & 31;
        float acc = qb[o];
#pragma unroll
        for (int f = 0; f < FF; ++f) {
            const float xv = xs[r * FF + f];
            const float qv = (xv >= 0.f) ? qs[0][f * OO + o]
                                         : qs[1][f * OO + o];
            acc = fmaf(xv, qv, acc);
        }
        f_sums[(n0 + r) * OO + o] = acc;
        return;
    }

    // ---- exact fallback: wave-per-node, 2 passes ----
    const int wave = t >> 6;
    const int lane = t & 63;
    for (int pass = 0; pass < 2; ++pass) {
        const int n = n0 + pass * 4 + wave;
        const int f = lane;
        const float xv = x[n * FF + f];

        float h1[HH];
#pragma unroll
        for (int h = 0; h < HH; ++h)
            h1[h] = fmaxf(xv * fW1[f * HH + h] + fb1[f * HH + h], 0.f);

        float h2[HH];
#pragma unroll
        for (int g = 0; g < HH; ++g) h2[g] = fb2[f * HH + g];
#pragma unroll
        for (int h = 0; h < HH; ++h) {
            const float a = h1[h];
            const float* __restrict__ w = &fW2[(f * HH + h) * HH];
#pragma unroll
            for (int g = 0; g < HH; ++g) h2[g] += a * w[g];
        }
#pragma unroll
        for (int g = 0; g < HH; ++g) h2[g] = fmaxf(h2[g], 0.f);

        float acc[OO];
#pragma unroll
        for (int o = 0; o < OO; ++o) acc[o] = fb3[f * OO + o];
#pragma unroll
        for (int h = 0; h < HH; ++h) {
            const float a = h2[h];
            const float* __restrict__ w = &fW3[(f * HH + h) * OO];
#pragma unroll
            for (int o = 0; o < OO; ++o) acc[o] += a * w[o];
        }

#pragma unroll
        for (int o = 0; o < OO; ++o) {
            float v = acc[o];
#pragma unroll
            for (int off = 32; off >= 1; off >>= 1)
                v += __shfl_xor(v, off, 64);
            acc[o] = v;
        }
        if (lane == 0) {
#pragma unroll
            for (int o = 0; o < OO; ++o)
                f_sums[n * OO + o] = acc[o];
        }
    }
}

// ---------------------------------------------------------------------------
// Kernel 3: rho + normalize + matmul. 1024 blocks (32 row-tiles x 32
// k-splits), 64x64 tiles, 24.5 KB LDS -> 4 blocks/CU for latency hiding.
// float4 staging of dmat/norm; atomicAdd into pre-zeroed out.
// ---------------------------------------------------------------------------
__global__ __launch_bounds__(256) void rho_all_kernel(
    const float* __restrict__ dmat, const float* __restrict__ norm,
    const float* __restrict__ f_sums,
    const float* __restrict__ cpr, const float* __restrict__ rb3,
    const float* __restrict__ rW1, const float* __restrict__ rb1,
    const float* __restrict__ rW2, const float* __restrict__ rb2,
    const float* __restrict__ rW3,
    const int* __restrict__ flags,
    float* __restrict__ out)
{
    const int t = threadIdx.x;

    if (flags[1]) {
        __shared__ float Bt[64 * 66];    // [j][r], padded stride 66 (16.5 KB)
        __shared__ float fsL[64 * 32];   // [j][o] (8 KB)

        const int rt = blockIdx.x >> 5;  // 0..31
        const int kb = blockIdx.x & 31;  // 0..31
        const int n0 = rt * 64;
        const int m0 = kb * 64;

        const float cp = cpr[0], cn = cpr[1], b3 = rb3[0];

        // stage f_sums chunk: 512 float4
        {
            const float4* src = (const float4*)&f_sums[m0 * OO];
            float4* dst = (float4*)fsL;
#pragma unroll
            for (int i = 0; i < 2; ++i)
                dst[i * 256 + t] = src[i * 256 + t];
        }

        // stage B tile: 64 rows x 16 float4-groups, 4 iters
#pragma unroll
        for (int it = 0; it < 4; ++it) {
            const int idx4 = it * 256 + t;
            const int r = idx4 >> 4;              // row within tile
            const int j4 = (idx4 & 15) * 4;       // first col of the group
            const long g = (long)(n0 + r) * NN + (m0 + j4);
            const float4 d4 = *(const float4*)&dmat[g];
            const float4 n4 = *(const float4*)&norm[g];
            Bt[(j4 + 0) * 66 + r] =
                fmaf(d4.x >= 0.f ? cp : cn, d4.x, b3) / n4.x;
            Bt[(j4 + 1) * 66 + r] =
                fmaf(d4.y >= 0.f ? cp : cn, d4.y, b3) / n4.y;
            Bt[(j4 + 2) * 66 + r] =
                fmaf(d4.z >= 0.f ? cp : cn, d4.z, b3) / n4.z;
            Bt[(j4 + 3) * 66 + r] =
                fmaf(d4.w >= 0.f ? cp : cn, d4.w, b3) / n4.w;
        }
        __syncthreads();

        const int oq = t & 7;
        const int rg = t >> 3;
        const int r0 = rg * 2;

        float4 acc0 = make_float4(0.f, 0.f, 0.f, 0.f);
        float4 acc1 = make_float4(0.f, 0.f, 0.f, 0.f);

#pragma unroll 4
        for (int j = 0; j < 64; ++j) {
            const float2 b  = *(const float2*)&Bt[j * 66 + r0];
            const float4 fv = *(const float4*)&fsL[j * 32 + oq * 4];
            acc0.x = fmaf(b.x, fv.x, acc0.x);
            acc0.y = fmaf(b.x, fv.y, acc0.y);
            acc0.z = fmaf(b.x, fv.z, acc0.z);
            acc0.w = fmaf(b.x, fv.w, acc0.w);
            acc1.x = fmaf(b.y, fv.x, acc1.x);
            acc1.y = fmaf(b.y, fv.y, acc1.y);
            acc1.z = fmaf(b.y, fv.z, acc1.z);
            acc1.w = fmaf(b.y, fv.w, acc1.w);
        }

        float* p = &out[(n0 + r0) * OO + oq * 4];
        atomicAdd(p + 0, acc0.x);
        atomicAdd(p + 1, acc0.y);
        atomicAdd(p + 2, acc0.z);
        atomicAdd(p + 3, acc0.w);
        atomicAdd(p + OO + 0, acc1.x);
        atomicAdd(p + OO + 1, acc1.y);
        atomicAdd(p + OO + 2, acc1.z);
        atomicAdd(p + OO + 3, acc1.w);
        return;
    }

    // ---- exact fallback: first 512 blocks, 4 rows each, full K ----
    if (blockIdx.x >= 512) return;
    __shared__ float red[4][OO];
    const int wave = t >> 6;
    const int lane = t & 63;

    for (int rr = 0; rr < 4; ++rr) {
        const int n = blockIdx.x * 4 + rr;

        float acc[OO];
#pragma unroll
        for (int o = 0; o < OO; ++o) acc[o] = 0.f;

#pragma unroll 1
        for (int m0 = 0; m0 < NN; m0 += 256) {
            const int m = m0 + t;
            const float d = dmat[(long)n * NN + m];

            float h1[HH];
#pragma unroll
            for (int h = 0; h < HH; ++h)
                h1[h] = fmaxf(d * rW1[h] + rb1[h], 0.f);

            float h2[HH];
#pragma unroll
            for (int g = 0; g < HH; ++g) h2[g] = rb2[g];
#pragma unroll
            for (int h = 0; h < HH; ++h) {
                const float a = h1[h];
#pragma unroll
                for (int g = 0; g < HH; ++g) h2[g] += a * rW2[h * HH + g];
            }

            float r = rb3[0];
#pragma unroll
            for (int h = 0; h < HH; ++h)
                r += fmaxf(h2[h], 0.f) * rW3[h];

            r /= norm[(long)n * NN + m];

            const float* __restrict__ fs = &f_sums[m * OO];
#pragma unroll
            for (int o = 0; o < OO; ++o) acc[o] += r * fs[o];
        }

#pragma unroll
        for (int o = 0; o < OO; ++o) {
            float v = acc[o];
#pragma unroll
            for (int off = 32; off >= 1; off >>= 1)
                v += __shfl_xor(v, off, 64);
            acc[o] = v;
        }
        if (lane == 0) {
#pragma unroll
            for (int o = 0; o < OO; ++o) red[wave][o] = acc[o];
        }
        __syncthreads();
        if (t < OO)
            out[n * OO + t] = red[0][t] + red[1][t] + red[2][t] + red[3][t];
        __syncthreads();
    }
}

extern "C" void kernel_launch(void* const* d_in, const int* in_sizes, int n_in,
                              void* d_out, int out_size, void* d_ws, size_t ws_size,
                              hipStream_t stream) {
    const float* x    = (const float*)d_in[0];
    const float* dmat = (const float*)d_in[1];
    const float* norm = (const float*)d_in[2];
    const float* fW1  = (const float*)d_in[3];
    const float* fb1  = (const float*)d_in[4];
    const float* fW2  = (const float*)d_in[5];
    const float* fb2  = (const float*)d_in[6];
    const float* fW3  = (const float*)d_in[7];
    const float* fb3  = (const float*)d_in[8];
    const float* rW1  = (const float*)d_in[9];
    const float* rb1  = (const float*)d_in[10];
    const float* rW2  = (const float*)d_in[11];
    const float* rb2  = (const float*)d_in[12];
    const float* rW3  = (const float*)d_in[13];
    const float* rb3  = (const float*)d_in[14];

    char* ws = (char*)d_ws;
    float* f_sums = (float*)(ws + WS_FSUMS);
    float* q_pos  = (float*)(ws + WS_QPOS);
    float* q_neg  = (float*)(ws + WS_QNEG);
    float* qb     = (float*)(ws + WS_QB);
    float* cpr    = (float*)(ws + WS_CPR);
    int*   flags  = (int*)(ws + WS_FLAGS);

    float* out = (float*)d_out;

    precompute_all_kernel<<<FF + 1, 256, 0, stream>>>(
        fW1, fb1, fW2, fb2, fW3, fb3, rW1, rb1, rW2, rb2, rW3,
        q_pos, q_neg, qb, cpr, flags, out);

    fsums_all_kernel<<<NN / 8, 256, 0, stream>>>(
        x, q_pos, q_neg, qb, fW1, fb1, fW2, fb2, fW3, fb3, flags, f_sums);

    rho_all_kernel<<<1024, 256, 0, stream>>>(
        dmat, norm, f_sums, cpr, rb3, rW1, rb1, rW2, rb2, rW3, flags, out);
}

// Round 8
// 126.300 us; speedup vs baseline: 1.1746x; 1.0753x over previous
//
#include <hip/hip_runtime.h>

#define NN 2048
#define FF 64
#define HH 32
#define OO 32

// Workspace layout (bytes):
//   0      : f_sums [2048*32] f32  (256 KB)
//   262144 : q_pos  [64*32] f32
//   270336 : q_neg  [64*32] f32
//   278528 : qb     [32] f32
//   278656 : cpr    [2] f32
//   278664 : flags  [2] int
#define WS_FSUMS 0
#define WS_QPOS  262144
#define WS_QNEG  270336
#define WS_QB    278528
#define WS_CPR   278656
#define WS_FLAGS 278664

// Tuning journal:
//  R5 (this structure): 127.97 us  <- best
//  R6 spin-barrier fusion of k1+k2: +20 us (cross-XCD flag polling)
//  R7 rho k-split 16->32 (64x64 tiles): +8 us (halved arithmetic intensity)
// => 512-block rho (64x128 tiles, 16 k-splits) + 3 separate launches is the
//    floor configuration; remaining wall time is harness poison/restore.

// ---------------------------------------------------------------------------
// Kernel 1: precompute + zero out.  Blocks 0..63: per-feature q tables
// (LDS-staged float4 loads). Block 64: cpr/qb/flags.
// ---------------------------------------------------------------------------
__global__ __launch_bounds__(256) void precompute_all_kernel(
    const float* __restrict__ fW1, const float* __restrict__ fb1,
    const float* __restrict__ fW2, const float* __restrict__ fb2,
    const float* __restrict__ fW3, const float* __restrict__ fb3,
    const float* __restrict__ rW1, const float* __restrict__ rb1,
    const float* __restrict__ rW2, const float* __restrict__ rb2,
    const float* __restrict__ rW3,
    float* __restrict__ q_pos, float* __restrict__ q_neg,
    float* __restrict__ qb, float* __restrict__ cpr,
    int* __restrict__ flags, float* __restrict__ out)
{
    __shared__ float sA[HH * HH];      // fW2 slab / rW2
    __shared__ float sB[FF * OO];      // fW3 slab (1024) / fb3 (2048)
    __shared__ float sC[128];          // vs / vsr + small weights
    __shared__ int sflags[2];

    const int t = threadIdx.x;

    if (blockIdx.x < FF) {
        const int f = blockIdx.x;
        ((float4*)out)[blockIdx.x * 256 + t] =
            make_float4(0.f, 0.f, 0.f, 0.f);
        ((float4*)sA)[t] = ((const float4*)&fW2[f * HH * HH])[t];
        ((float4*)sB)[t] = ((const float4*)&fW3[f * HH * OO])[t];
        if (t < HH) sC[64 + t] = fW1[f * HH + t];
        __syncthreads();

        if (t < 64) {
            const int s = t >> 5;      // 0=pos, 1=neg
            const int g = t & 31;
            float v = 0.f;
#pragma unroll
            for (int h = 0; h < HH; ++h) {
                const float w1 = sC[64 + h];
                const float a = s ? fminf(w1, 0.f) : fmaxf(w1, 0.f);
                v = fmaf(a, sA[h * HH + g], v);
            }
            sC[t] = s ? fminf(v, 0.f) : fmaxf(v, 0.f);
        }
        __syncthreads();
        if (t < 64) {
            const int s = t >> 5;
            const int o = t & 31;
            float q = 0.f;
#pragma unroll
            for (int g = 0; g < HH; ++g)
                q = fmaf(sC[s * 32 + g], sB[g * OO + o], q);
            if (s) q_neg[f * OO + o] = q;
            else   q_pos[f * OO + o] = q;
        }
        return;
    }

    // ---- block 64: misc ----
    if (t == 0) { sflags[0] = 1; sflags[1] = 1; }
    ((float4*)sA)[t] = ((const float4*)rW2)[t];
    ((float4*)sB)[t] = ((const float4*)fb3)[t];
    ((float4*)sB)[t + 256] = ((const float4*)fb3)[t + 256];
    if (t < HH) sC[64 + t] = rW1[t];
    else if (t < 64) sC[96 + (t - HH)] = rW3[t - HH];
    __syncthreads();

    if (t < 64) {
        const int s = t >> 5;
        const int g = t & 31;
        float v = 0.f;
#pragma unroll
        for (int h = 0; h < HH; ++h) {
            const float w1 = sC[64 + h];
            const float a = s ? fminf(w1, 0.f) : fmaxf(w1, 0.f);
            v = fmaf(a, sA[h * HH + g], v);
        }
        sC[t] = s ? fminf(v, 0.f) : fmaxf(v, 0.f);
    } else if (t < 96) {
        const int o = t - 64;
        float a = 0.f;
#pragma unroll
        for (int f = 0; f < FF; ++f) a += sB[f * OO + o];
        qb[o] = a;
    } else if (t < 160) {
        const int i = t - 96;
        bool bad;
        if (i < HH) bad = (rb1[i] != 0.f);
        else        bad = (rb2[i - HH] != 0.f);
        if (bad) sflags[1] = 0;
    } else {
        const float4* b1 = (const float4*)fb1;
        const float4* b2 = (const float4*)fb2;
        bool bad = false;
        for (int i = t - 160; i < (FF * HH) / 4; i += 96) {
            const float4 a = b1[i], b = b2[i];
            bad |= (a.x != 0.f) | (a.y != 0.f) | (a.z != 0.f) | (a.w != 0.f);
            bad |= (b.x != 0.f) | (b.y != 0.f) | (b.z != 0.f) | (b.w != 0.f);
        }
        if (bad) sflags[0] = 0;
    }
    __syncthreads();

    if (t < 2) {
        float c = 0.f;
#pragma unroll
        for (int g = 0; g < HH; ++g)
            c = fmaf(sC[t * 32 + g], sC[96 + g], c);
        cpr[t] = c;
    }
    if (t == 0) { flags[0] = sflags[0]; flags[1] = sflags[1]; }
}

// ---------------------------------------------------------------------------
// Kernel 2: f_sums. Fast path: stage q tables (16 KB) + x (2 KB) into LDS
// with float4 cooperative loads; inner loop pure LDS. 256 blocks x 8 nodes.
// ---------------------------------------------------------------------------
__global__ __launch_bounds__(256) void fsums_all_kernel(
    const float* __restrict__ x,
    const float* __restrict__ q_pos, const float* __restrict__ q_neg,
    const float* __restrict__ qb,
    const float* __restrict__ fW1, const float* __restrict__ fb1,
    const float* __restrict__ fW2, const float* __restrict__ fb2,
    const float* __restrict__ fW3, const float* __restrict__ fb3,
    const int* __restrict__ flags,
    float* __restrict__ f_sums)
{
    const int t = threadIdx.x;
    const int n0 = blockIdx.x * 8;

    if (flags[0]) {
        __shared__ float qs[2][FF * OO];   // 2 x 8 KB
        __shared__ float xs[8 * FF];       // 2 KB
        ((float4*)qs[0])[t]       = ((const float4*)q_pos)[t];
        ((float4*)qs[0])[t + 256] = ((const float4*)q_pos)[t + 256];
        ((float4*)qs[1])[t]       = ((const float4*)q_neg)[t];
        ((float4*)qs[1])[t + 256] = ((const float4*)q_neg)[t + 256];
        if (t < 128) ((float4*)xs)[t] = ((const float4*)&x[n0 * FF])[t];
        __syncthreads();

        const int r = t >> 5;
        const int o = t & 31;
        float acc = qb[o];
#pragma unroll
        for (int f = 0; f < FF; ++f) {
            const float xv = xs[r * FF + f];
            const float qv = (xv >= 0.f) ? qs[0][f * OO + o]
                                         : qs[1][f * OO + o];
            acc = fmaf(xv, qv, acc);
        }
        f_sums[(n0 + r) * OO + o] = acc;
        return;
    }

    // ---- exact fallback: wave-per-node, 2 passes ----
    const int wave = t >> 6;
    const int lane = t & 63;
    for (int pass = 0; pass < 2; ++pass) {
        const int n = n0 + pass * 4 + wave;
        const int f = lane;
        const float xv = x[n * FF + f];

        float h1[HH];
#pragma unroll
        for (int h = 0; h < HH; ++h)
            h1[h] = fmaxf(xv * fW1[f * HH + h] + fb1[f * HH + h], 0.f);

        float h2[HH];
#pragma unroll
        for (int g = 0; g < HH; ++g) h2[g] = fb2[f * HH + g];
#pragma unroll
        for (int h = 0; h < HH; ++h) {
            const float a = h1[h];
            const float* __restrict__ w = &fW2[(f * HH + h) * HH];
#pragma unroll
            for (int g = 0; g < HH; ++g) h2[g] += a * w[g];
        }
#pragma unroll
        for (int g = 0; g < HH; ++g) h2[g] = fmaxf(h2[g], 0.f);

        float acc[OO];
#pragma unroll
        for (int o = 0; o < OO; ++o) acc[o] = fb3[f * OO + o];
#pragma unroll
        for (int h = 0; h < HH; ++h) {
            const float a = h2[h];
            const float* __restrict__ w = &fW3[(f * HH + h) * OO];
#pragma unroll
            for (int o = 0; o < OO; ++o) acc[o] += a * w[o];
        }

#pragma unroll
        for (int o = 0; o < OO; ++o) {
            float v = acc[o];
#pragma unroll
            for (int off = 32; off >= 1; off >>= 1)
                v += __shfl_xor(v, off, 64);
            acc[o] = v;
        }
        if (lane == 0) {
#pragma unroll
            for (int o = 0; o < OO; ++o)
                f_sums[n * OO + o] = acc[o];
        }
    }
}

// ---------------------------------------------------------------------------
// Kernel 3: rho + normalize + matmul. 512 blocks (32 row-tiles x 16 k-splits),
// 64x128 tiles (R5 best config). float4 staging of dmat/norm, fast rcp for
// the normalize (norm in [1,2], rel err ~2^-22 vs 0.1875 threshold);
// atomicAdd into the pre-zeroed out.
// ---------------------------------------------------------------------------
__global__ __launch_bounds__(256) void rho_all_kernel(
    const float* __restrict__ dmat, const float* __restrict__ norm,
    const float* __restrict__ f_sums,
    const float* __restrict__ cpr, const float* __restrict__ rb3,
    const float* __restrict__ rW1, const float* __restrict__ rb1,
    const float* __restrict__ rW2, const float* __restrict__ rb2,
    const float* __restrict__ rW3,
    const int* __restrict__ flags,
    float* __restrict__ out)
{
    const int t = threadIdx.x;

    if (flags[1]) {
        __shared__ float Bt[128 * 66];   // [j][r], padded stride 66
        __shared__ float fsL[128 * 32];  // [j][o]

        const int rt = blockIdx.x >> 4;  // 0..31
        const int kb = blockIdx.x & 15;  // 0..15
        const int n0 = rt * 64;
        const int m0 = kb * 128;

        const float cp = cpr[0], cn = cpr[1], b3 = rb3[0];

        {
            const float4* src = (const float4*)&f_sums[m0 * OO];
            float4* dst = (float4*)fsL;
#pragma unroll
            for (int i = 0; i < 4; ++i)
                dst[i * 256 + t] = src[i * 256 + t];
        }

#pragma unroll
        for (int it = 0; it < 8; ++it) {
            const int idx4 = it * 256 + t;
            const int r = idx4 >> 5;
            const int j4 = (idx4 & 31) * 4;
            const long g = (long)(n0 + r) * NN + (m0 + j4);
            const float4 d4 = *(const float4*)&dmat[g];
            const float4 n4 = *(const float4*)&norm[g];
            Bt[(j4 + 0) * 66 + r] =
                fmaf(d4.x >= 0.f ? cp : cn, d4.x, b3) * __builtin_amdgcn_rcpf(n4.x);
            Bt[(j4 + 1) * 66 + r] =
                fmaf(d4.y >= 0.f ? cp : cn, d4.y, b3) * __builtin_amdgcn_rcpf(n4.y);
            Bt[(j4 + 2) * 66 + r] =
                fmaf(d4.z >= 0.f ? cp : cn, d4.z, b3) * __builtin_amdgcn_rcpf(n4.z);
            Bt[(j4 + 3) * 66 + r] =
                fmaf(d4.w >= 0.f ? cp : cn, d4.w, b3) * __builtin_amdgcn_rcpf(n4.w);
        }
        __syncthreads();

        const int oq = t & 7;
        const int rg = t >> 3;
        const int r0 = rg * 2;

        float4 acc0 = make_float4(0.f, 0.f, 0.f, 0.f);
        float4 acc1 = make_float4(0.f, 0.f, 0.f, 0.f);

#pragma unroll 4
        for (int j = 0; j < 128; ++j) {
            const float2 b  = *(const float2*)&Bt[j * 66 + r0];
            const float4 fv = *(const float4*)&fsL[j * 32 + oq * 4];
            acc0.x = fmaf(b.x, fv.x, acc0.x);
            acc0.y = fmaf(b.x, fv.y, acc0.y);
            acc0.z = fmaf(b.x, fv.z, acc0.z);
            acc0.w = fmaf(b.x, fv.w, acc0.w);
            acc1.x = fmaf(b.y, fv.x, acc1.x);
            acc1.y = fmaf(b.y, fv.y, acc1.y);
            acc1.z = fmaf(b.y, fv.z, acc1.z);
            acc1.w = fmaf(b.y, fv.w, acc1.w);
        }

        float* p = &out[(n0 + r0) * OO + oq * 4];
        atomicAdd(p + 0, acc0.x);
        atomicAdd(p + 1, acc0.y);
        atomicAdd(p + 2, acc0.z);
        atomicAdd(p + 3, acc0.w);
        atomicAdd(p + OO + 0, acc1.x);
        atomicAdd(p + OO + 1, acc1.y);
        atomicAdd(p + OO + 2, acc1.z);
        atomicAdd(p + OO + 3, acc1.w);
        return;
    }

    // ---- exact fallback: 4 rows per block, full K ----
    __shared__ float red[4][OO];
    const int wave = t >> 6;
    const int lane = t & 63;

    for (int rr = 0; rr < 4; ++rr) {
        const int n = blockIdx.x * 4 + rr;

        float acc[OO];
#pragma unroll
        for (int o = 0; o < OO; ++o) acc[o] = 0.f;

#pragma unroll 1
        for (int m0 = 0; m0 < NN; m0 += 256) {
            const int m = m0 + t;
            const float d = dmat[(long)n * NN + m];

            float h1[HH];
#pragma unroll
            for (int h = 0; h < HH; ++h)
                h1[h] = fmaxf(d * rW1[h] + rb1[h], 0.f);

            float h2[HH];
#pragma unroll
            for (int g = 0; g < HH; ++g) h2[g] = rb2[g];
#pragma unroll
            for (int h = 0; h < HH; ++h) {
                const float a = h1[h];
#pragma unroll
                for (int g = 0; g < HH; ++g) h2[g] += a * rW2[h * HH + g];
            }

            float r = rb3[0];
#pragma unroll
            for (int h = 0; h < HH; ++h)
                r += fmaxf(h2[h], 0.f) * rW3[h];

            r /= norm[(long)n * NN + m];

            const float* __restrict__ fs = &f_sums[m * OO];
#pragma unroll
            for (int o = 0; o < OO; ++o) acc[o] += r * fs[o];
        }

#pragma unroll
        for (int o = 0; o < OO; ++o) {
            float v = acc[o];
#pragma unroll
            for (int off = 32; off >= 1; off >>= 1)
                v += __shfl_xor(v, off, 64);
            acc[o] = v;
        }
        if (lane == 0) {
#pragma unroll
            for (int o = 0; o < OO; ++o) red[wave][o] = acc[o];
        }
        __syncthreads();
        if (t < OO)
            out[n * OO + t] = red[0][t] + red[1][t] + red[2][t] + red[3][t];
        __syncthreads();
    }
}

extern "C" void kernel_launch(void* const* d_in, const int* in_sizes, int n_in,
                              void* d_out, int out_size, void* d_ws, size_t ws_size,
                              hipStream_t stream) {
    const float* x    = (const float*)d_in[0];
    const float* dmat = (const float*)d_in[1];
    const float* norm = (const float*)d_in[2];
    const float* fW1  = (const float*)d_in[3];
    const float* fb1  = (const float*)d_in[4];
    const float* fW2  = (const float*)d_in[5];
    const float* fb2  = (const float*)d_in[6];
    const float* fW3  = (const float*)d_in[7];
    const float* fb3  = (const float*)d_in[8];
    const float* rW1  = (const float*)d_in[9];
    const float* rb1  = (const float*)d_in[10];
    const float* rW2  = (const float*)d_in[11];
    const float* rb2  = (const float*)d_in[12];
    const float* rW3  = (const float*)d_in[13];
    const float* rb3  = (const float*)d_in[14];

    char* ws = (char*)d_ws;
    float* f_sums = (float*)(ws + WS_FSUMS);
    float* q_pos  = (float*)(ws + WS_QPOS);
    float* q_neg  = (float*)(ws + WS_QNEG);
    float* qb     = (float*)(ws + WS_QB);
    float* cpr    = (float*)(ws + WS_CPR);
    int*   flags  = (int*)(ws + WS_FLAGS);

    float* out = (float*)d_out;

    precompute_all_kernel<<<FF + 1, 256, 0, stream>>>(
        fW1, fb1, fW2, fb2, fW3, fb3, rW1, rb1, rW2, rb2, rW3,
        q_pos, q_neg, qb, cpr, flags, out);

    fsums_all_kernel<<<NN / 8, 256, 0, stream>>>(
        x, q_pos, q_neg, qb, fW1, fb1, fW2, fb2, fW3, fb3, flags, f_sums);

    rho_all_kernel<<<512, 256, 0, stream>>>(
        dmat, norm, f_sums, cpr, rb3, rW1, rb1, rW2, rb2, rW3, flags, out);
}